// Round 1
// baseline (353.735 us; speedup 1.0000x reference)
//
#include <hip/hip_runtime.h>
#include <math.h>

#define NBINS 32
#define NB2   1024      // 32*32
#define EPSD  1e-8
#define MAXB  1024      // max blocks for kernel 1 (partials sized for this)

// ws layout:
//   [0,      8192)  : double ent_part[MAXB]
//   [8192,  12288)  : uint   cnt_part[MAXB]
//   [12288, ...  )  : uint   hist_part[B][1024]
// Every block fully writes its partial slots each launch -> no ws zero-init needed.

__device__ inline double block_reduce_sum_d(double v, double* sh) {
#pragma unroll
    for (int o = 32; o > 0; o >>= 1) v += __shfl_down(v, o, 64);
    const int lane = threadIdx.x & 63;
    const int wave = threadIdx.x >> 6;
    const int nw   = blockDim.x >> 6;
    __syncthreads();                       // protect sh from previous use
    if (lane == 0) sh[wave] = v;
    __syncthreads();
    double r = (threadIdx.x < nw) ? sh[threadIdx.x] : 0.0;
    if (wave == 0) {
#pragma unroll
        for (int o = 8; o > 0; o >>= 1) r += __shfl_down(r, o, 64);
    }
    return r;  // valid in thread 0
}

extern "C" __global__ void __launch_bounds__(256)
topo_hist_kernel(const float* __restrict__ stu, const float* __restrict__ tea,
                 const float* __restrict__ unc,
                 unsigned int* __restrict__ hist_part,
                 double* __restrict__ ent_part,
                 unsigned int* __restrict__ cnt_part,
                 int n)
{
    __shared__ unsigned int sh_hist[NB2];
    __shared__ double sh_red[4];

    for (int i = threadIdx.x; i < NB2; i += blockDim.x) sh_hist[i] = 0u;
    __syncthreads();

    double ent = 0.0;
    unsigned int cnt = 0;

    const int n4     = n >> 2;
    const int gid    = blockIdx.x * blockDim.x + threadIdx.x;
    const int stride = gridDim.x * blockDim.x;

    const float4* s4 = (const float4*)stu;
    const float4* t4 = (const float4*)tea;
    const float4* u4 = (const float4*)unc;

    for (int i = gid; i < n4; i += stride) {
        float4 s = s4[i];
        float4 t = t4[i];
        float4 u = u4[i];
        float sv[4] = {s.x, s.y, s.z, s.w};
        float tv[4] = {t.x, t.y, t.z, t.w};
        float uv[4] = {u.x, u.y, u.z, u.w};
#pragma unroll
        for (int k = 0; k < 4; ++k) {
            float topo = 1.0f - fabsf(sv[k] - tv[k]);   // in (0, 1]
            float conf = 1.0f - uv[k];                  // in (0, 1]
            // exact: *32 is an exponent shift, edges are exact k/32
            int ti = (int)(topo * 32.0f);
            int ci = (int)(conf * 32.0f);
            if (ti < NBINS && ci < NBINS)
                atomicAdd(&sh_hist[(ti << 5) + ci], 1u);
            if (conf > 0.8f) {
                cnt++;
                float tc = fminf(fmaxf(topo, 1e-8f), 1.0f - 1e-8f);
                ent += (double)(-tc * logf(tc + 1e-8f));
            }
        }
    }
    // tail (n not multiple of 4) — robustness; no-op for 4096^2
    for (int i = (n4 << 2) + gid; i < n; i += stride) {
        float topo = 1.0f - fabsf(stu[i] - tea[i]);
        float conf = 1.0f - unc[i];
        int ti = (int)(topo * 32.0f);
        int ci = (int)(conf * 32.0f);
        if (ti < NBINS && ci < NBINS)
            atomicAdd(&sh_hist[(ti << 5) + ci], 1u);
        if (conf > 0.8f) {
            cnt++;
            float tc = fminf(fmaxf(topo, 1e-8f), 1.0f - 1e-8f);
            ent += (double)(-tc * logf(tc + 1e-8f));
        }
    }

    __syncthreads();
    for (int i = threadIdx.x; i < NB2; i += blockDim.x)
        hist_part[(size_t)blockIdx.x * NB2 + i] = sh_hist[i];

    double es = block_reduce_sum_d(ent, sh_red);
    double cs = block_reduce_sum_d((double)cnt, sh_red);
    if (threadIdx.x == 0) {
        ent_part[blockIdx.x] = es;
        cnt_part[blockIdx.x] = (unsigned int)(cs + 0.5);
    }
}

extern "C" __global__ void __launch_bounds__(1024)
topo_final_kernel(const unsigned int* __restrict__ hist_part,
                  const double* __restrict__ ent_part,
                  const unsigned int* __restrict__ cnt_part,
                  int B, float* __restrict__ out)
{
    __shared__ double sh_red[16];
    __shared__ double jp[NB2];
    __shared__ double marg_r[NBINS];
    __shared__ double marg_c[NBINS];
    __shared__ double bcast;

    const int tid = threadIdx.x;

    // sum per-bin counts over B partials (coalesced: consecutive tid -> consecutive addr)
    unsigned int c = 0;
    for (int b = 0; b < B; ++b) c += hist_part[(size_t)b * NB2 + tid];
    double dc = (double)c;

    double total = block_reduce_sum_d(dc, sh_red);
    if (tid == 0) bcast = total;
    __syncthreads();
    total = bcast;

    double p = dc / (total + EPSD);
    jp[tid] = p;
    __syncthreads();

    if (tid < NBINS) {
        double s = 0.0;
        for (int cc = 0; cc < NBINS; ++cc) s += jp[(tid << 5) + cc];
        marg_r[tid] = s;
    } else if (tid < 2 * NBINS) {
        int cc = tid - NBINS;
        double s = 0.0;
        for (int r = 0; r < NBINS; ++r) s += jp[(r << 5) + cc];
        marg_c[cc] = s;
    }
    __syncthreads();

    const int r  = tid >> 5;
    const int cc = tid & 31;
    double term = 0.0;
    if (p > EPSD)
        term = p * log(p / (marg_r[r] * marg_c[cc] + EPSD) + EPSD);
    double mi = block_reduce_sum_d(term, sh_red);

    double ev = (tid < B) ? ent_part[tid] : 0.0;
    double es = block_reduce_sum_d(ev, sh_red);
    double cv = (tid < B) ? (double)cnt_part[tid] : 0.0;
    double cs = block_reduce_sum_d(cv, sh_red);

    if (tid == 0) {
        double mi_v     = (total < EPSD) ? 0.0 : mi;
        double mean     = es / fmax(cs, 1.0);
        double ent_loss = (cs > 10.0) ? mean : 0.0;
        out[0] = (float)(-mi_v + 0.1 * ent_loss);
    }
}

extern "C" void kernel_launch(void* const* d_in, const int* in_sizes, int n_in,
                              void* d_out, int out_size, void* d_ws, size_t ws_size,
                              hipStream_t stream) {
    const float* stu = (const float*)d_in[0];
    const float* tea = (const float*)d_in[1];
    const float* unc = (const float*)d_in[2];
    float* out = (float*)d_out;
    int n = in_sizes[0];

    int B = MAXB;  // 1024 blocks x 256 threads = 4 blocks/CU
    size_t need = 12288 + (size_t)B * NB2 * sizeof(unsigned int);
    if (ws_size < need) {
        B = (ws_size > 12288) ? (int)((ws_size - 12288) / (NB2 * sizeof(unsigned int))) : 1;
        if (B < 1) B = 1;
        if (B > MAXB) B = MAXB;
    }

    double*       ent_part  = (double*)d_ws;
    unsigned int* cnt_part  = (unsigned int*)((char*)d_ws + 8192);
    unsigned int* hist_part = (unsigned int*)((char*)d_ws + 12288);

    topo_hist_kernel<<<B, 256, 0, stream>>>(stu, tea, unc, hist_part, ent_part, cnt_part, n);
    topo_final_kernel<<<1, 1024, 0, stream>>>(hist_part, ent_part, cnt_part, B, out);
}

// Round 2
// 214.503 us; speedup vs baseline: 1.6491x; 1.6491x over previous
//
#include <hip/hip_runtime.h>
#include <math.h>

#define NBINS 32
#define NB2   1024      // 32*32
#define EPSD  1e-8

// ws layout (tiny now):
//   [0,    4096) : uint   ghist[1024]   (global joint histogram)
//   [4096, 4104) : double gent          (entropy sum)
//   [4104, 4108) : uint   gcnt          (high-conf count)
// ws is poisoned 0xAA before every launch -> zero_kernel initializes it.

__device__ inline double block_reduce_sum_d(double v, double* sh) {
#pragma unroll
    for (int o = 32; o > 0; o >>= 1) v += __shfl_down(v, o, 64);
    const int lane = threadIdx.x & 63;
    const int wave = threadIdx.x >> 6;
    const int nw   = blockDim.x >> 6;
    __syncthreads();
    if (lane == 0) sh[wave] = v;
    __syncthreads();
    double r = (threadIdx.x < nw) ? sh[threadIdx.x] : 0.0;
    if (wave == 0) {
#pragma unroll
        for (int o = 8; o > 0; o >>= 1) r += __shfl_down(r, o, 64);
    }
    return r;  // valid in thread 0
}

extern "C" __global__ void __launch_bounds__(1024)
topo_zero_kernel(unsigned int* __restrict__ ghist,
                 double* __restrict__ gent,
                 unsigned int* __restrict__ gcnt)
{
    ghist[threadIdx.x] = 0u;
    if (threadIdx.x == 0) { *gent = 0.0; *gcnt = 0u; }
}

extern "C" __global__ void __launch_bounds__(256)
topo_hist_kernel(const float* __restrict__ stu, const float* __restrict__ tea,
                 const float* __restrict__ unc,
                 unsigned int* __restrict__ ghist,
                 double* __restrict__ gent,
                 unsigned int* __restrict__ gcnt,
                 int n)
{
    __shared__ unsigned int sh_hist[4 * NB2];   // one 1024-bin sub-hist per wave
    __shared__ double sh_red[4];

    const int wave = threadIdx.x >> 6;
    unsigned int* myh = sh_hist + wave * NB2;

    for (int i = threadIdx.x; i < 4 * NB2; i += blockDim.x) sh_hist[i] = 0u;
    __syncthreads();

    double ent = 0.0;
    unsigned int cnt = 0;

    const int n4     = n >> 2;
    const int gid    = blockIdx.x * blockDim.x + threadIdx.x;
    const int stride = gridDim.x * blockDim.x;

    const float4* s4 = (const float4*)stu;
    const float4* t4 = (const float4*)tea;
    const float4* u4 = (const float4*)unc;

    for (int i = gid; i < n4; i += stride) {
        float4 s = s4[i];
        float4 t = t4[i];
        float4 u = u4[i];
        float sv[4] = {s.x, s.y, s.z, s.w};
        float tv[4] = {t.x, t.y, t.z, t.w};
        float uv[4] = {u.x, u.y, u.z, u.w};
#pragma unroll
        for (int k = 0; k < 4; ++k) {
            float topo = 1.0f - fabsf(sv[k] - tv[k]);   // (0, 1]
            float conf = 1.0f - uv[k];                  // (0, 1]
            int ti = (int)(topo * 32.0f);               // exact binning
            int ci = (int)(conf * 32.0f);
            if (ti < NBINS && ci < NBINS)
                atomicAdd(&myh[(ti << 5) + ci], 1u);
            // branchless entropy: wave executes this path ~always anyway
            bool hc = conf > 0.8f;
            float tc = fminf(fmaxf(topo, 1e-8f), 1.0f - 1e-8f);
            float e  = -tc * __logf(tc + 1e-8f);
            ent += hc ? (double)e : 0.0;
            cnt += hc ? 1u : 0u;
        }
    }
    // tail (robustness; no-op for 4096^2)
    for (int i = (n4 << 2) + gid; i < n; i += stride) {
        float topo = 1.0f - fabsf(stu[i] - tea[i]);
        float conf = 1.0f - unc[i];
        int ti = (int)(topo * 32.0f);
        int ci = (int)(conf * 32.0f);
        if (ti < NBINS && ci < NBINS)
            atomicAdd(&myh[(ti << 5) + ci], 1u);
        bool hc = conf > 0.8f;
        float tc = fminf(fmaxf(topo, 1e-8f), 1.0f - 1e-8f);
        float e  = -tc * __logf(tc + 1e-8f);
        ent += hc ? (double)e : 0.0;
        cnt += hc ? 1u : 0u;
    }

    __syncthreads();
    // flush: sum 4 sub-hists, one global atomic per bin (coalesced per wave)
    for (int b = threadIdx.x; b < NB2; b += blockDim.x) {
        unsigned int v = sh_hist[b] + sh_hist[NB2 + b] +
                         sh_hist[2 * NB2 + b] + sh_hist[3 * NB2 + b];
        if (v) atomicAdd(&ghist[b], v);
    }

    double es = block_reduce_sum_d(ent, sh_red);
    double cs = block_reduce_sum_d((double)cnt, sh_red);
    if (threadIdx.x == 0) {
        atomicAdd(gent, es);
        atomicAdd(gcnt, (unsigned int)(cs + 0.5));
    }
}

extern "C" __global__ void __launch_bounds__(1024)
topo_final_kernel(const unsigned int* __restrict__ ghist,
                  const double* __restrict__ gent,
                  const unsigned int* __restrict__ gcnt,
                  float* __restrict__ out)
{
    __shared__ double sh_red[16];
    __shared__ double jp[NB2];
    __shared__ double marg_r[NBINS];
    __shared__ double marg_c[NBINS];
    __shared__ double bcast;

    const int tid = threadIdx.x;

    double dc = (double)ghist[tid];

    double total = block_reduce_sum_d(dc, sh_red);
    if (tid == 0) bcast = total;
    __syncthreads();
    total = bcast;

    double p = dc / (total + EPSD);
    jp[tid] = p;
    __syncthreads();

    if (tid < NBINS) {
        double s = 0.0;
        for (int cc = 0; cc < NBINS; ++cc) s += jp[(tid << 5) + cc];
        marg_r[tid] = s;
    } else if (tid < 2 * NBINS) {
        int cc = tid - NBINS;
        double s = 0.0;
        for (int r = 0; r < NBINS; ++r) s += jp[(r << 5) + cc];
        marg_c[cc] = s;
    }
    __syncthreads();

    const int r  = tid >> 5;
    const int cc = tid & 31;
    double term = 0.0;
    if (p > EPSD)
        term = p * log(p / (marg_r[r] * marg_c[cc] + EPSD) + EPSD);
    double mi = block_reduce_sum_d(term, sh_red);

    if (tid == 0) {
        double es = *gent;
        double cs = (double)(*gcnt);
        double mi_v     = (total < EPSD) ? 0.0 : mi;
        double mean     = es / fmax(cs, 1.0);
        double ent_loss = (cs > 10.0) ? mean : 0.0;
        out[0] = (float)(-mi_v + 0.1 * ent_loss);
    }
}

extern "C" void kernel_launch(void* const* d_in, const int* in_sizes, int n_in,
                              void* d_out, int out_size, void* d_ws, size_t ws_size,
                              hipStream_t stream) {
    const float* stu = (const float*)d_in[0];
    const float* tea = (const float*)d_in[1];
    const float* unc = (const float*)d_in[2];
    float* out = (float*)d_out;
    int n = in_sizes[0];

    unsigned int* ghist = (unsigned int*)d_ws;
    double*       gent  = (double*)((char*)d_ws + 4096);
    unsigned int* gcnt  = (unsigned int*)((char*)d_ws + 4104);

    const int B = 1024;  // 4 blocks/CU on 256 CUs

    topo_zero_kernel<<<1, 1024, 0, stream>>>(ghist, gent, gcnt);
    topo_hist_kernel<<<B, 256, 0, stream>>>(stu, tea, unc, ghist, gent, gcnt, n);
    topo_final_kernel<<<1, 1024, 0, stream>>>(ghist, gent, gcnt, out);
}